// Round 1
// baseline (582.237 us; speedup 1.0000x reference)
//
#include <hip/hip_runtime.h>
#include <stdint.h>

#define BS 128
#define SL 512
#define HD 1024
#define DD 512
#define M_TOT (BS*SL)   // 65536

typedef __attribute__((ext_vector_type(8))) short short8;
typedef __attribute__((ext_vector_type(4))) float f32x4;

__device__ __forceinline__ unsigned short f32_bf16(float f) {
    union { float f; unsigned u; } v; v.f = f;
    unsigned u = v.u + 0x7FFFu + ((v.u >> 16) & 1u);
    return (unsigned short)(u >> 16);
}
__device__ __forceinline__ float bf16_f32(unsigned short h) {
    union { unsigned u; float f; } v; v.u = ((unsigned)h) << 16; return v.f;
}

// ---------------- mask dtype detection ----------------
// mask may arrive as int32 (0/1 words) or uint8 (packed bools). Reading the
// first 1024 words: if any word value > 1, it's byte-packed bools.
__global__ void detect_mask_kernel(const unsigned* mw, int* flag) {
    int t = threadIdx.x;
    unsigned bad = 0;
    for (int i = t; i < 1024; i += 256) bad |= (mw[i] > 1u) ? 1u : 0u;
    if (bad) atomicExch(flag, 1);
}

// ---------------- pack Wq into bf16 hi/lo, MFMA-frag order ----------------
// Tile (nb in 0..3, ks in 0..31): 16KB block = 4096 hi halves + 4096 lo halves.
// Within: colgroup cg (16 cols), lane l: n = nb*128+cg*16+(l&15),
// k = ks*32+(l>>4)*8+j  -> half index (cg*64+l)*8+j.
__global__ void pack_wq_kernel(const float* __restrict__ Wq,
                               unsigned short* __restrict__ P) {
    int t = blockIdx.x * 256 + threadIdx.x;   // 0..65535
    int d  = t >> 7;           // 0..511
    int h0 = (t & 127) << 3;   // 0..1016
    const float* src = Wq + (size_t)d * HD + h0;
    unsigned short hi[8], lo[8];
#pragma unroll
    for (int j = 0; j < 8; ++j) {
        float f = src[j];
        hi[j] = f32_bf16(f);
        lo[j] = f32_bf16(f - bf16_f32(hi[j]));
    }
    int nb = d >> 7, cg = (d >> 4) & 7, lr = d & 15;
    int ks = h0 >> 5, q = (h0 >> 3) & 3;
    int l = q * 16 + lr;
    size_t base = (size_t)(nb * 32 + ks) * 8192 + (size_t)(cg * 64 + l) * 8;
    union { unsigned short s[8]; uint4 v; } a, b;
#pragma unroll
    for (int j = 0; j < 8; ++j) { a.s[j] = hi[j]; b.s[j] = lo[j]; }
    *(uint4*)(P + base)        = a.v;
    *(uint4*)(P + base + 4096) = b.v;
}

// ---------------- phase 1: score = vq . tanh(x @ Wq^T + bq) ----------------
// 128x128 tile, K=1024 in 32 steps of 32. 4 waves, each 64x64 (4x4 tiles of
// 16x16). 3-term bf16 split: a = xh*Wh + xl*Wh + xh*Wl (fp32-quality).
__launch_bounds__(256, 2)
__global__ void score_kernel(const float* __restrict__ x,
                             const unsigned short* __restrict__ packW,
                             const float* __restrict__ bq,
                             const float* __restrict__ vq,
                             float* __restrict__ score) {
    __shared__ unsigned short A_hi[4096];   // 8 KB, frag order
    __shared__ unsigned short A_lo[4096];   // 8 KB
    __shared__ unsigned short Bt[8192];     // 16 KB: hi[0..4095], lo[4096..]

    const int nb = blockIdx.x;          // 0..3  (N tile of 128)
    const int m0 = blockIdx.y * 128;    // row tile
    const int t = threadIdx.x;
    const int l = t & 63;
    const int w = t >> 6;
    const int wm = w & 1, wn = w >> 1;  // 2x2 wave grid, each 64x64

    f32x4 acc[4][4];
#pragma unroll
    for (int i = 0; i < 4; ++i)
#pragma unroll
        for (int j = 0; j < 4; ++j)
            acc[i][j] = (f32x4){0.f, 0.f, 0.f, 0.f};

    const uint4* bsrc_base = (const uint4*)packW;

    for (int ks = 0; ks < 32; ++ks) {
        __syncthreads();
        // ---- stage A: 128 rows x 32 k fp32 -> bf16 hi/lo in frag order ----
#pragma unroll
        for (int r = 0; r < 4; ++r) {
            int idx = r * 256 + t;          // 0..1023 float4s
            int row = idx >> 3, c4 = idx & 7;
            const float4* xp = (const float4*)(x + (size_t)(m0 + row) * HD + ks * 32);
            float4 v = xp[c4];
            unsigned short h[4], lo4[4];
            float ff[4] = {v.x, v.y, v.z, v.w};
#pragma unroll
            for (int j = 0; j < 4; ++j) {
                h[j]  = f32_bf16(ff[j]);
                lo4[j] = f32_bf16(ff[j] - bf16_f32(h[j]));
            }
            int rg = row >> 4, rr = row & 15, q = c4 >> 1, j0 = (c4 & 1) * 4;
            int off = (rg * 64 + q * 16 + rr) * 8 + j0;
            *(uint2*)&A_hi[off] = make_uint2((unsigned)h[0] | ((unsigned)h[1] << 16),
                                             (unsigned)h[2] | ((unsigned)h[3] << 16));
            *(uint2*)&A_lo[off] = make_uint2((unsigned)lo4[0] | ((unsigned)lo4[1] << 16),
                                             (unsigned)lo4[2] | ((unsigned)lo4[3] << 16));
        }
        // ---- stage B: linear 16KB copy (already frag-ordered) ----
        {
            const uint4* src = bsrc_base + (size_t)(nb * 32 + ks) * 1024;
            uint4* dst = (uint4*)Bt;
#pragma unroll
            for (int r = 0; r < 4; ++r) dst[r * 256 + t] = src[r * 256 + t];
        }
        __syncthreads();

        // ---- compute ----
        const short8* Ah = (const short8*)A_hi;
        const short8* Al = (const short8*)A_lo;
        const short8* Bh = (const short8*)Bt;
        const short8* Bl = (const short8*)(Bt + 4096);
        short8 ah[4], al[4], bh[4], bl[4];
#pragma unroll
        for (int i = 0; i < 4; ++i) {
            ah[i] = Ah[(wm * 4 + i) * 64 + l];
            al[i] = Al[(wm * 4 + i) * 64 + l];
        }
#pragma unroll
        for (int j = 0; j < 4; ++j) {
            bh[j] = Bh[(wn * 4 + j) * 64 + l];
            bl[j] = Bl[(wn * 4 + j) * 64 + l];
        }
#pragma unroll
        for (int i = 0; i < 4; ++i)
#pragma unroll
            for (int j = 0; j < 4; ++j) {
                acc[i][j] = __builtin_amdgcn_mfma_f32_16x16x32_bf16(ah[i], bh[j], acc[i][j], 0, 0, 0);
                acc[i][j] = __builtin_amdgcn_mfma_f32_16x16x32_bf16(al[i], bh[j], acc[i][j], 0, 0, 0);
                acc[i][j] = __builtin_amdgcn_mfma_f32_16x16x32_bf16(ah[i], bl[j], acc[i][j], 0, 0, 0);
            }
    }

    // ---- epilogue: + bq, tanh, *vq, reduce over cols, atomicAdd ----
    // C/D layout (verified): col = lane&15, row = (lane>>4)*4 + reg
    int q = l >> 4, c = l & 15;
#pragma unroll
    for (int i = 0; i < 4; ++i) {
        float rs[4] = {0.f, 0.f, 0.f, 0.f};
#pragma unroll
        for (int j = 0; j < 4; ++j) {
            int n = nb * 128 + wn * 64 + j * 16 + c;
            float bqv = bq[n], vqv = vq[n];
            f32x4 a4 = acc[i][j];
#pragma unroll
            for (int r = 0; r < 4; ++r)
                rs[r] += tanhf(a4[r] + bqv) * vqv;
        }
#pragma unroll
        for (int r = 0; r < 4; ++r) {
            float v = rs[r];
            v += __shfl_xor(v, 1);
            v += __shfl_xor(v, 2);
            v += __shfl_xor(v, 4);
            v += __shfl_xor(v, 8);
            if (c == 0)
                atomicAdd(&score[m0 + wm * 64 + i * 16 + q * 4 + r], v);
        }
    }
}

// ---------------- phase 2: masked softmax over sl=512 ----------------
__global__ void softmax_kernel(const float* __restrict__ score,
                               const void* __restrict__ maskp,
                               const int* __restrict__ flag,
                               float* __restrict__ wgt) {
    __shared__ float red[8];
    int b = blockIdx.x, t = threadIdx.x;
    int w = t >> 6, l = t & 63;
    bool u8 = (*flag != 0);
    int i0 = b * SL + t, i1 = i0 + 256;
    bool mk0, mk1;
    if (u8) {
        mk0 = ((const unsigned char*)maskp)[i0] != 0;
        mk1 = ((const unsigned char*)maskp)[i1] != 0;
    } else {
        mk0 = ((const int*)maskp)[i0] != 0;
        mk1 = ((const int*)maskp)[i1] != 0;
    }
    float s0 = mk0 ? -1000000.0f : score[i0];
    float s1 = mk1 ? -1000000.0f : score[i1];
    float mx = fmaxf(s0, s1);
    for (int d = 1; d < 64; d <<= 1) mx = fmaxf(mx, __shfl_xor(mx, d));
    if (l == 0) red[w] = mx;
    __syncthreads();
    mx = fmaxf(fmaxf(red[0], red[1]), fmaxf(red[2], red[3]));
    float e0 = expf(s0 - mx), e1 = expf(s1 - mx);
    float sm = e0 + e1;
    for (int d = 1; d < 64; d <<= 1) sm += __shfl_xor(sm, d);
    if (l == 0) red[4 + w] = sm;
    __syncthreads();
    sm = red[4] + red[5] + red[6] + red[7];
    float inv = 1.0f / sm;
    wgt[i0] = e0 * inv;
    wgt[i1] = e1 * inv;
}

// ---------------- phase 3: res[b,h] = sum_s w[b,s]*x[b,s,h] ----------------
__global__ void wsum_kernel(const float* __restrict__ x,
                            const float* __restrict__ wgt,
                            float* __restrict__ out) {
    __shared__ float wsh[64];
    int b = blockIdx.x, sc = blockIdx.y, t = threadIdx.x;
    if (t < 64) wsh[t] = wgt[b * SL + sc * 64 + t];
    __syncthreads();
    const float4* xp = (const float4*)(x + ((size_t)b * SL + sc * 64) * HD) + t;
    float ax = 0.f, ay = 0.f, az = 0.f, aw = 0.f;
#pragma unroll 4
    for (int s = 0; s < 64; ++s) {
        float wv = wsh[s];
        float4 v = xp[(size_t)s * 256];
        ax += wv * v.x; ay += wv * v.y; az += wv * v.z; aw += wv * v.w;
    }
    float* dst = out + (size_t)b * HD + t * 4;
    atomicAdd(dst + 0, ax);
    atomicAdd(dst + 1, ay);
    atomicAdd(dst + 2, az);
    atomicAdd(dst + 3, aw);
}

extern "C" void kernel_launch(void* const* d_in, const int* in_sizes, int n_in,
                              void* d_out, int out_size, void* d_ws, size_t ws_size,
                              hipStream_t stream) {
    const float* x  = (const float*)d_in[0];
    const void* mask = d_in[1];
    const float* Wq = (const float*)d_in[2];
    const float* bq = (const float*)d_in[3];
    const float* vq = (const float*)d_in[4];
    float* out = (float*)d_out;

    char* ws = (char*)d_ws;
    unsigned short* packW = (unsigned short*)ws;                    // 2 MB
    float* score = (float*)(ws + (2u << 20));                       // 256 KB
    float* wgt   = (float*)(ws + (2u << 20) + (256u << 10));        // 256 KB
    int*   flag  = (int*)  (ws + (2u << 20) + (512u << 10));        // 4 B

    hipMemsetAsync(score, 0, M_TOT * sizeof(float), stream);
    hipMemsetAsync(flag, 0, sizeof(int), stream);
    hipMemsetAsync(d_out, 0, (size_t)out_size * sizeof(float), stream);

    detect_mask_kernel<<<1, 256, 0, stream>>>((const unsigned*)mask, flag);
    pack_wq_kernel<<<256, 256, 0, stream>>>(Wq, packW);
    score_kernel<<<dim3(4, 512), 256, 0, stream>>>(x, packW, bq, vq, score);
    softmax_kernel<<<BS, 256, 0, stream>>>(score, mask, flag, wgt);
    wsum_kernel<<<dim3(BS, 8), 256, 0, stream>>>(x, wgt, out);
}